// Round 17
// baseline (235.340 us; speedup 1.0000x reference)
//
#include <hip/hip_runtime.h>
#include <hip/hip_bf16.h>

#define E_ 32
#define H_ 1024
#define I_ 768
#define I2_ 1536
#define T_ 4096
#define K_ 4
#define CAP_ 1024
#define NSLOT_ (E_*CAP_)

typedef __attribute__((ext_vector_type(8))) short short8;
typedef __attribute__((ext_vector_type(4))) short short4v;
typedef __attribute__((ext_vector_type(4))) float f32x4;

__device__ __forceinline__ short f2bf(float f) {
    __hip_bfloat16 h = __float2bfloat16(f);
    return __builtin_bit_cast(short, h);
}

__device__ __forceinline__ float bf2f(short s) {
    unsigned u = ((unsigned)(unsigned short)s) << 16;
    return __builtin_bit_cast(float, u);
}

typedef __attribute__((address_space(3))) void lds_void;
typedef const __attribute__((address_space(1))) void glob_void;

__device__ __forceinline__ void gload16(const void* g, void* l) {
    __builtin_amdgcn_global_load_lds((glob_void*)g, (lds_void*)l, 16, 0, 0);
}

__device__ __forceinline__ short8 cvt8(f32x4 x, f32x4 y) {
    short8 t;
    t[0]=f2bf(x[0]); t[1]=f2bf(x[1]); t[2]=f2bf(x[2]); t[3]=f2bf(x[3]);
    t[4]=f2bf(y[0]); t[5]=f2bf(y[1]); t[6]=f2bf(y[2]); t[7]=f2bf(y[3]);
    return t;
}

// ---------------- fused init + hidden-state cast ----------------
__global__ void k_initcast(const float* __restrict__ hs, short* __restrict__ Xb,
                           int* __restrict__ cursor, int* __restrict__ s_tok,
                           float* __restrict__ s_w) {
    int g = blockIdx.x * 256 + threadIdx.x;
    if (g < E_) cursor[g] = 0;
    if (g < NSLOT_) { s_tok[g] = 0; s_w[g] = 0.f; }
    const float* p = hs + (size_t)g * 8;
    f32x4 a = *(const f32x4*)p;
    f32x4 b = *(const f32x4*)(p + 4);
    *(short8*)(Xb + (size_t)g * 8) = cvt8(a, b);
}

__global__ void k_scatter(const int* __restrict__ tki, const float* __restrict__ tkw,
                          int* __restrict__ cursor, int* __restrict__ s_tok,
                          float* __restrict__ s_w, int* __restrict__ pos) {
    int n = blockIdx.x * 256 + threadIdx.x;
    if (n >= T_ * K_) return;
    int e = tki[n];
    int p = atomicAdd(cursor + e, 1);
    if (p < CAP_) {
        s_tok[e * CAP_ + p] = n >> 2;   // K_ == 4
        s_w[e * CAP_ + p]   = tkw[n];
        pos[n] = e * CAP_ + p;
    } else {
        pos[n] = -1;                    // dropped (matches reference overflow semantics)
    }
}

// ---------------- GEMM1 + SwiGLU (BK=32, 24 KB LDS for residency) ----------------
// Block 128 rows x (128 gate + 128 up), BK=32, 512 threads = 8 waves (2M x 4N).
// Wave: 64 rows x (32g + 32u) -> 16 MFMA/K-step. 32 K-steps.
// Swizzle: 4 chunks/row, stored pos = logical ^ ((row>>1)&3), both sides.
__global__ __launch_bounds__(512, 4) void k_gemm1(
    const short* __restrict__ Xb, const float* __restrict__ W1,
    const int* __restrict__ s_tok, const int* __restrict__ counts,
    short* __restrict__ Hb)
{
    __shared__ alignas(16) short As[128 * 32];   // 8 KB
    __shared__ alignas(16) short Bs[256 * 32];   // 16 KB: rows 0-127 gate, 128-255 up

    int bid = blockIdx.x;
    bid = (bid & 7) * (1536 / 8) + (bid >> 3);   // T1 bijective XCD swizzle

    int e   = bid / 48;                          // 8 mt * 6 nt
    int rem = bid % 48;
    int mt = rem / 6, nt = rem % 6;
    int cnt = min(counts[e], CAP_);
    int row0 = mt * 128;
    if (row0 >= cnt) return;
    int gc0 = nt * 128;

    int tid = threadIdx.x, wid = tid >> 6, lane = tid & 63;
    int wm = wid >> 2, wn = wid & 3;

    // A: 1 x 16B chunk/thread (512 chunks; 4 chunks per 32-bf16 row).
    int rowA = tid >> 2, cposA = tid & 3;
    int tokA = s_tok[e * CAP_ + row0 + rowA];
    unsigned offA = (unsigned)tokA * H_ + ((cposA ^ ((rowA >> 1) & 3)) * 8);

    // B: 2 bf16-chunks/thread (1024 chunks; each from 2 fp32x4 loads).
    const float* w1e = W1 + (size_t)e * I2_ * H_;
    unsigned gB[2]; unsigned ldsB[2];
#pragma unroll
    for (int j = 0; j < 2; ++j) {
        int cl = j * 512 + tid;
        int row = cl >> 2, cpos = cl & 3;       // row 0..255
        int wr = (row < 128) ? (gc0 + row) : (768 + gc0 + (row - 128));
        gB[j]   = (unsigned)wr * H_ + cpos * 8;
        ldsB[j] = (unsigned)row * 32 + ((cpos ^ ((row >> 1) & 3)) * 8);
    }

    f32x4 accg[4][2], accu[4][2];
#pragma unroll
    for (int m = 0; m < 4; ++m)
#pragma unroll
        for (int n = 0; n < 2; ++n) {
            accg[m][n] = (f32x4){0.f, 0.f, 0.f, 0.f};
            accu[m][n] = (f32x4){0.f, 0.f, 0.f, 0.f};
        }

    for (int kt = 0; kt < H_ / 32; ++kt) {
        int k0 = kt * 32;
        f32x4 b0[2], b1[2];
#pragma unroll
        for (int j = 0; j < 2; ++j) {
            const float* p = w1e + gB[j] + k0;
            b0[j] = *(const f32x4*)p;
            b1[j] = *(const f32x4*)(p + 4);
        }
        gload16(Xb + offA + k0, (char*)As + wid * 1024);
#pragma unroll
        for (int j = 0; j < 2; ++j)
            *(short8*)&Bs[ldsB[j]] = cvt8(b0[j], b1[j]);
        __syncthreads();

        {
            short8 a[4];
#pragma unroll
            for (int m = 0; m < 4; ++m) {
                int r = wm * 64 + m * 16 + (lane & 15);
                int c = (lane >> 4) ^ ((r >> 1) & 3);
                a[m] = *(const short8*)&As[r * 32 + c * 8];
            }
            short8 bg[2], bu[2];
#pragma unroll
            for (int n = 0; n < 2; ++n) {
                int brg = wn * 32 + n * 16 + (lane & 15);
                int cg = (lane >> 4) ^ ((brg >> 1) & 3);
                bg[n] = *(const short8*)&Bs[brg * 32 + cg * 8];
                int bru = 128 + wn * 32 + n * 16 + (lane & 15);
                int cu = (lane >> 4) ^ ((bru >> 1) & 3);
                bu[n] = *(const short8*)&Bs[bru * 32 + cu * 8];
            }
#pragma unroll
            for (int m = 0; m < 4; ++m)
#pragma unroll
                for (int n = 0; n < 2; ++n) {
                    accg[m][n] = __builtin_amdgcn_mfma_f32_16x16x32_bf16(a[m], bg[n], accg[m][n], 0, 0, 0);
                    accu[m][n] = __builtin_amdgcn_mfma_f32_16x16x32_bf16(a[m], bu[n], accu[m][n], 0, 0, 0);
                }
        }
        __syncthreads();
    }

    // SwiGLU epilogue
#pragma unroll
    for (int m = 0; m < 4; ++m) {
        int rb = row0 + wm * 64 + m * 16 + ((lane >> 4) * 4);
#pragma unroll
        for (int n = 0; n < 2; ++n) {
            int col = gc0 + wn * 32 + n * 16 + (lane & 15);
#pragma unroll
            for (int q = 0; q < 4; ++q) {
                float g = accg[m][n][q], u = accu[m][n][q];
                float h = (g / (1.f + __expf(-g))) * u;
                Hb[(size_t)(e * CAP_ + rb + q) * I_ + col] = f2bf(h);
            }
        }
    }
}

// ---------------- GEMM2 -> Oslot bf16 (r16-proven) ----------------
// Block 256 rows x 128 H-cols, BK=64, 512 threads = 8 waves (4M x 2N); wave 64x64. 48 KB LDS.
__global__ __launch_bounds__(512) void k_gemm2(
    const short* __restrict__ Hb, const float* __restrict__ W2,
    const float* __restrict__ s_w, const int* __restrict__ counts,
    short* __restrict__ Oslot)
{
    __shared__ alignas(16) short Ah[256 * 64];   // 32 KB
    __shared__ alignas(16) short Bs[128 * 64];   // 16 KB

    int bid = blockIdx.x;
    bid = (bid & 7) * (1024 / 8) + (bid >> 3);   // T1 bijective XCD swizzle

    int e = bid / 32;                            // 4 mt * 8 nt
    int rem = bid % 32;
    int mt = rem / 8, nt = rem % 8;
    int cnt = min(counts[e], CAP_);
    int row0 = mt * 256;
    if (row0 >= cnt) return;
    int nc0 = nt * 128;

    int tid = threadIdx.x, wid = tid >> 6, lane = tid & 63;
    int wm = wid >> 1, wn = wid & 1;

    unsigned offA[4];
#pragma unroll
    for (int j = 0; j < 4; ++j) {
        int cl = j * 512 + tid;
        int row = cl >> 3, cpos = cl & 7;
        offA[j] = (unsigned)(e * CAP_ + row0 + row) * I_ + ((cpos ^ (row & 7)) * 8);
    }
    const float* w2e = W2 + (size_t)e * H_ * I_;
    unsigned gB[2]; unsigned ldsB[2];
#pragma unroll
    for (int j = 0; j < 2; ++j) {
        int cl = j * 512 + tid;
        int row = cl >> 3, cpos = cl & 7;
        gB[j]   = (unsigned)(nc0 + row) * I_ + cpos * 8;
        ldsB[j] = (unsigned)row * 64 + ((cpos ^ (row & 7)) * 8);
    }

    f32x4 acc[4][4];
#pragma unroll
    for (int m = 0; m < 4; ++m)
#pragma unroll
        for (int n = 0; n < 4; ++n) acc[m][n] = (f32x4){0.f, 0.f, 0.f, 0.f};

    for (int kt = 0; kt < I_ / 64; ++kt) {
        int k0 = kt * 64;
        f32x4 b0[2], b1[2];
#pragma unroll
        for (int j = 0; j < 2; ++j) {
            const float* p = w2e + gB[j] + k0;
            b0[j] = *(const f32x4*)p;
            b1[j] = *(const f32x4*)(p + 4);
        }
#pragma unroll
        for (int j = 0; j < 4; ++j)
            gload16(Hb + offA[j] + k0, (char*)Ah + j * 8192 + wid * 1024);
#pragma unroll
        for (int j = 0; j < 2; ++j)
            *(short8*)&Bs[ldsB[j]] = cvt8(b0[j], b1[j]);
        __syncthreads();

#pragma unroll
        for (int kk = 0; kk < 2; ++kk) {
            short8 a[4];
#pragma unroll
            for (int m = 0; m < 4; ++m) {
                int r = wm * 64 + m * 16 + (lane & 15);
                int c = (kk * 4 + (lane >> 4)) ^ (r & 7);
                a[m] = *(const short8*)&Ah[r * 64 + c * 8];
            }
            short8 b[4];
#pragma unroll
            for (int n = 0; n < 4; ++n) {
                int br = wn * 64 + n * 16 + (lane & 15);
                int c = (kk * 4 + (lane >> 4)) ^ (br & 7);
                b[n] = *(const short8*)&Bs[br * 64 + c * 8];
            }
#pragma unroll
            for (int m = 0; m < 4; ++m)
#pragma unroll
                for (int n = 0; n < 4; ++n)
                    acc[m][n] = __builtin_amdgcn_mfma_f32_16x16x32_bf16(a[m], b[n], acc[m][n], 0, 0, 0);
        }
        __syncthreads();
    }

#pragma unroll
    for (int m = 0; m < 4; ++m) {
#pragma unroll
        for (int q = 0; q < 4; ++q) {
            int i = row0 + wm * 64 + m * 16 + ((lane >> 4) * 4) + q;
            if (i < cnt) {
                float w = s_w[e * CAP_ + i];
                short* orow = Oslot + (size_t)(e * CAP_ + i) * H_;
#pragma unroll
                for (int n = 0; n < 4; ++n)
                    orow[nc0 + wn * 64 + n * 16 + (lane & 15)] = f2bf(acc[m][n][q] * w);
            }
        }
    }
}

// ---------------- gather: out[t] = sum_k Oslot[pos[t,k]] (bf16 in, fp32 out) ----------------
__global__ __launch_bounds__(256) void k_gather(
    const short* __restrict__ Oslot, const int* __restrict__ pos,
    float* __restrict__ out)
{
    int t = blockIdx.x;
    int c = threadIdx.x * 4;
    int p0 = pos[t * 4 + 0], p1 = pos[t * 4 + 1];
    int p2 = pos[t * 4 + 2], p3 = pos[t * 4 + 3];
    f32x4 s = (f32x4){0.f, 0.f, 0.f, 0.f};
    if (p0 >= 0) {
        short4v v = *(const short4v*)&Oslot[(size_t)p0 * H_ + c];
        s[0] += bf2f(v[0]); s[1] += bf2f(v[1]); s[2] += bf2f(v[2]); s[3] += bf2f(v[3]);
    }
    if (p1 >= 0) {
        short4v v = *(const short4v*)&Oslot[(size_t)p1 * H_ + c];
        s[0] += bf2f(v[0]); s[1] += bf2f(v[1]); s[2] += bf2f(v[2]); s[3] += bf2f(v[3]);
    }
    if (p2 >= 0) {
        short4v v = *(const short4v*)&Oslot[(size_t)p2 * H_ + c];
        s[0] += bf2f(v[0]); s[1] += bf2f(v[1]); s[2] += bf2f(v[2]); s[3] += bf2f(v[3]);
    }
    if (p3 >= 0) {
        short4v v = *(const short4v*)&Oslot[(size_t)p3 * H_ + c];
        s[0] += bf2f(v[0]); s[1] += bf2f(v[1]); s[2] += bf2f(v[2]); s[3] += bf2f(v[3]);
    }
    *(f32x4*)&out[(size_t)t * H_ + c] = s;
}

// ---------------- launch ----------------

extern "C" void kernel_launch(void* const* d_in, const int* in_sizes, int n_in,
                              void* d_out, int out_size, void* d_ws, size_t ws_size,
                              hipStream_t stream) {
    const float* hs  = (const float*)d_in[0];
    const int*   tki = (const int*)d_in[1];
    const float* tkw = (const float*)d_in[2];
    const float* w1  = (const float*)d_in[3];
    const float* w2  = (const float*)d_in[4];
    float* out = (float*)d_out;

    char* ws = (char*)d_ws;
    int*   cursor = (int*)ws;                                  // 4 KB region
    int*   s_tok  = (int*)(ws + 4096);                         // 128 KB
    float* s_w    = (float*)(ws + 4096 + NSLOT_ * 4);          // 128 KB
    int*   pos    = (int*)(ws + 4096 + NSLOT_ * 8);            // 64 KB
    char*  big0   = ws + 4096 + NSLOT_ * 8 + (size_t)T_ * K_ * 4;
    short* Xb     = (short*)big0;                              // 8 MB
    short* Hb     = (short*)(big0 + (size_t)T_ * H_ * 2);      // 48 MB
    short* Oslot  = (short*)(big0 + (size_t)T_ * H_ * 2 + (size_t)NSLOT_ * I_ * 2); // 67 MB

    hipLaunchKernelGGL(k_initcast, dim3((T_ * H_) / 2048), dim3(256), 0, stream,
                       hs, Xb, cursor, s_tok, s_w);
    hipLaunchKernelGGL(k_scatter, dim3((T_ * K_) / 256), dim3(256), 0, stream,
                       tki, tkw, cursor, s_tok, s_w, pos);
    hipLaunchKernelGGL(k_gemm1, dim3(E_ * 8 * 6), dim3(512), 0, stream, Xb, w1, s_tok, cursor, Hb);
    hipLaunchKernelGGL(k_gemm2, dim3(E_ * 4 * 8), dim3(512), 0, stream, Hb, w2, s_w, cursor, Oslot);
    hipLaunchKernelGGL(k_gather, dim3(T_), dim3(256), 0, stream, Oslot, pos, out);
}

// Round 18
// 214.263 us; speedup vs baseline: 1.0984x; 1.0984x over previous
//
#include <hip/hip_runtime.h>
#include <hip/hip_bf16.h>

#define E_ 32
#define H_ 1024
#define I_ 768
#define I2_ 1536
#define T_ 4096
#define K_ 4
#define CAP_ 1024
#define NSLOT_ (E_*CAP_)

typedef __attribute__((ext_vector_type(8))) short short8;
typedef __attribute__((ext_vector_type(4))) short short4v;
typedef __attribute__((ext_vector_type(4))) float f32x4;

__device__ __forceinline__ short f2bf(float f) {
    __hip_bfloat16 h = __float2bfloat16(f);
    return __builtin_bit_cast(short, h);
}

__device__ __forceinline__ float bf2f(short s) {
    unsigned u = ((unsigned)(unsigned short)s) << 16;
    return __builtin_bit_cast(float, u);
}

typedef __attribute__((address_space(3))) void lds_void;
typedef const __attribute__((address_space(1))) void glob_void;

__device__ __forceinline__ void gload16(const void* g, void* l) {
    __builtin_amdgcn_global_load_lds((glob_void*)g, (lds_void*)l, 16, 0, 0);
}

__device__ __forceinline__ short8 cvt8(f32x4 x, f32x4 y) {
    short8 t;
    t[0]=f2bf(x[0]); t[1]=f2bf(x[1]); t[2]=f2bf(x[2]); t[3]=f2bf(x[3]);
    t[4]=f2bf(y[0]); t[5]=f2bf(y[1]); t[6]=f2bf(y[2]); t[7]=f2bf(y[3]);
    return t;
}

// ---------------- fused init + hidden-state cast ----------------
__global__ void k_initcast(const float* __restrict__ hs, short* __restrict__ Xb,
                           int* __restrict__ cursor, int* __restrict__ s_tok,
                           float* __restrict__ s_w) {
    int g = blockIdx.x * 256 + threadIdx.x;
    if (g < E_) cursor[g] = 0;
    if (g < NSLOT_) { s_tok[g] = 0; s_w[g] = 0.f; }
    const float* p = hs + (size_t)g * 8;
    f32x4 a = *(const f32x4*)p;
    f32x4 b = *(const f32x4*)(p + 4);
    *(short8*)(Xb + (size_t)g * 8) = cvt8(a, b);
}

__global__ void k_scatter(const int* __restrict__ tki, const float* __restrict__ tkw,
                          int* __restrict__ cursor, int* __restrict__ s_tok,
                          float* __restrict__ s_w, int* __restrict__ pos) {
    int n = blockIdx.x * 256 + threadIdx.x;
    if (n >= T_ * K_) return;
    int e = tki[n];
    int p = atomicAdd(cursor + e, 1);
    if (p < CAP_) {
        s_tok[e * CAP_ + p] = n >> 2;   // K_ == 4
        s_w[e * CAP_ + p]   = tkw[n];
        pos[n] = e * CAP_ + p;
    } else {
        pos[n] = -1;                    // dropped (matches reference overflow semantics)
    }
}

// ---------------- GEMM1 + SwiGLU (r15/r16-proven BN-doubled structure) ----------------
// Block 128 rows x (128 gate + 128 up), BK=64, 512 threads = 8 waves (2M x 4N).
__global__ __launch_bounds__(512) void k_gemm1(
    const short* __restrict__ Xb, const float* __restrict__ W1,
    const int* __restrict__ s_tok, const int* __restrict__ counts,
    short* __restrict__ Hb)
{
    __shared__ alignas(16) short As[128 * 64];   // 16 KB, ^(row&7) chunk swizzle
    __shared__ alignas(16) short Bs[256 * 64];   // 32 KB: rows 0-127 gate, 128-255 up

    int bid = blockIdx.x;
    bid = (bid & 7) * (1536 / 8) + (bid >> 3);   // T1 bijective XCD swizzle

    int e   = bid / 48;                          // 8 mt * 6 nt
    int rem = bid % 48;
    int mt = rem / 6, nt = rem % 6;
    int cnt = min(counts[e], CAP_);
    int row0 = mt * 128;
    if (row0 >= cnt) return;
    int gc0 = nt * 128;

    int tid = threadIdx.x, wid = tid >> 6, lane = tid & 63;
    int wm = wid >> 2, wn = wid & 3;

    unsigned offA[2];
#pragma unroll
    for (int j = 0; j < 2; ++j) {
        int cl = j * 512 + tid;
        int row = cl >> 3, cpos = cl & 7;
        int tok = s_tok[e * CAP_ + row0 + row];
        offA[j] = (unsigned)tok * H_ + ((cpos ^ (row & 7)) * 8);
    }
    const float* w1e = W1 + (size_t)e * I2_ * H_;
    unsigned gB[4]; unsigned ldsB[4];
#pragma unroll
    for (int j = 0; j < 4; ++j) {
        int cl = j * 512 + tid;
        int row = cl >> 3, cpos = cl & 7;       // row 0..255
        int wr = (row < 128) ? (gc0 + row) : (768 + gc0 + (row - 128));
        gB[j]   = (unsigned)wr * H_ + cpos * 8;
        ldsB[j] = (unsigned)row * 64 + ((cpos ^ (row & 7)) * 8);
    }

    f32x4 accg[4][2], accu[4][2];
#pragma unroll
    for (int m = 0; m < 4; ++m)
#pragma unroll
        for (int n = 0; n < 2; ++n) {
            accg[m][n] = (f32x4){0.f, 0.f, 0.f, 0.f};
            accu[m][n] = (f32x4){0.f, 0.f, 0.f, 0.f};
        }

    for (int kt = 0; kt < H_ / 64; ++kt) {
        int k0 = kt * 64;
        f32x4 b0[4], b1[4];
#pragma unroll
        for (int j = 0; j < 4; ++j) {
            const float* p = w1e + gB[j] + k0;
            b0[j] = *(const f32x4*)p;
            b1[j] = *(const f32x4*)(p + 4);
        }
#pragma unroll
        for (int j = 0; j < 2; ++j)
            gload16(Xb + offA[j] + k0, (char*)As + j * 8192 + wid * 1024);
#pragma unroll
        for (int j = 0; j < 4; ++j)
            *(short8*)&Bs[ldsB[j]] = cvt8(b0[j], b1[j]);
        __syncthreads();

#pragma unroll
        for (int kk = 0; kk < 2; ++kk) {
            short8 a[4];
#pragma unroll
            for (int m = 0; m < 4; ++m) {
                int r = wm * 64 + m * 16 + (lane & 15);
                int c = (kk * 4 + (lane >> 4)) ^ (r & 7);
                a[m] = *(const short8*)&As[r * 64 + c * 8];
            }
            short8 bg[2], bu[2];
#pragma unroll
            for (int n = 0; n < 2; ++n) {
                int brg = wn * 32 + n * 16 + (lane & 15);
                int cg = (kk * 4 + (lane >> 4)) ^ (brg & 7);
                bg[n] = *(const short8*)&Bs[brg * 64 + cg * 8];
                int bru = 128 + wn * 32 + n * 16 + (lane & 15);
                int cu = (kk * 4 + (lane >> 4)) ^ (bru & 7);
                bu[n] = *(const short8*)&Bs[bru * 64 + cu * 8];
            }
#pragma unroll
            for (int m = 0; m < 4; ++m)
#pragma unroll
                for (int n = 0; n < 2; ++n) {
                    accg[m][n] = __builtin_amdgcn_mfma_f32_16x16x32_bf16(a[m], bg[n], accg[m][n], 0, 0, 0);
                    accu[m][n] = __builtin_amdgcn_mfma_f32_16x16x32_bf16(a[m], bu[n], accu[m][n], 0, 0, 0);
                }
        }
        __syncthreads();
    }

    // SwiGLU epilogue
#pragma unroll
    for (int m = 0; m < 4; ++m) {
        int rb = row0 + wm * 64 + m * 16 + ((lane >> 4) * 4);
#pragma unroll
        for (int n = 0; n < 2; ++n) {
            int col = gc0 + wn * 32 + n * 16 + (lane & 15);
#pragma unroll
            for (int q = 0; q < 4; ++q) {
                float g = accg[m][n][q], u = accu[m][n][q];
                float h = (g / (1.f + __expf(-g))) * u;
                Hb[(size_t)(e * CAP_ + rb + q) * I_ + col] = f2bf(h);
            }
        }
    }
}

// ---------------- GEMM2 -> Oslot bf16 (r16-proven) ----------------
// Block 256 rows x 128 H-cols, BK=64, 512 threads = 8 waves (4M x 2N); wave 64x64. 48 KB LDS.
__global__ __launch_bounds__(512) void k_gemm2(
    const short* __restrict__ Hb, const float* __restrict__ W2,
    const float* __restrict__ s_w, const int* __restrict__ counts,
    short* __restrict__ Oslot)
{
    __shared__ alignas(16) short Ah[256 * 64];   // 32 KB
    __shared__ alignas(16) short Bs[128 * 64];   // 16 KB

    int bid = blockIdx.x;
    bid = (bid & 7) * (1024 / 8) + (bid >> 3);   // T1 bijective XCD swizzle

    int e = bid / 32;                            // 4 mt * 8 nt
    int rem = bid % 32;
    int mt = rem / 8, nt = rem % 8;
    int cnt = min(counts[e], CAP_);
    int row0 = mt * 256;
    if (row0 >= cnt) return;
    int nc0 = nt * 128;

    int tid = threadIdx.x, wid = tid >> 6, lane = tid & 63;
    int wm = wid >> 1, wn = wid & 1;

    unsigned offA[4];
#pragma unroll
    for (int j = 0; j < 4; ++j) {
        int cl = j * 512 + tid;
        int row = cl >> 3, cpos = cl & 7;
        offA[j] = (unsigned)(e * CAP_ + row0 + row) * I_ + ((cpos ^ (row & 7)) * 8);
    }
    const float* w2e = W2 + (size_t)e * H_ * I_;
    unsigned gB[2]; unsigned ldsB[2];
#pragma unroll
    for (int j = 0; j < 2; ++j) {
        int cl = j * 512 + tid;
        int row = cl >> 3, cpos = cl & 7;
        gB[j]   = (unsigned)(nc0 + row) * I_ + cpos * 8;
        ldsB[j] = (unsigned)row * 64 + ((cpos ^ (row & 7)) * 8);
    }

    f32x4 acc[4][4];
#pragma unroll
    for (int m = 0; m < 4; ++m)
#pragma unroll
        for (int n = 0; n < 4; ++n) acc[m][n] = (f32x4){0.f, 0.f, 0.f, 0.f};

    for (int kt = 0; kt < I_ / 64; ++kt) {
        int k0 = kt * 64;
        f32x4 b0[2], b1[2];
#pragma unroll
        for (int j = 0; j < 2; ++j) {
            const float* p = w2e + gB[j] + k0;
            b0[j] = *(const f32x4*)p;
            b1[j] = *(const f32x4*)(p + 4);
        }
#pragma unroll
        for (int j = 0; j < 4; ++j)
            gload16(Hb + offA[j] + k0, (char*)Ah + j * 8192 + wid * 1024);
#pragma unroll
        for (int j = 0; j < 2; ++j)
            *(short8*)&Bs[ldsB[j]] = cvt8(b0[j], b1[j]);
        __syncthreads();

#pragma unroll
        for (int kk = 0; kk < 2; ++kk) {
            short8 a[4];
#pragma unroll
            for (int m = 0; m < 4; ++m) {
                int r = wm * 64 + m * 16 + (lane & 15);
                int c = (kk * 4 + (lane >> 4)) ^ (r & 7);
                a[m] = *(const short8*)&Ah[r * 64 + c * 8];
            }
            short8 b[4];
#pragma unroll
            for (int n = 0; n < 4; ++n) {
                int br = wn * 64 + n * 16 + (lane & 15);
                int c = (kk * 4 + (lane >> 4)) ^ (br & 7);
                b[n] = *(const short8*)&Bs[br * 64 + c * 8];
            }
#pragma unroll
            for (int m = 0; m < 4; ++m)
#pragma unroll
                for (int n = 0; n < 4; ++n)
                    acc[m][n] = __builtin_amdgcn_mfma_f32_16x16x32_bf16(a[m], b[n], acc[m][n], 0, 0, 0);
        }
        __syncthreads();
    }

#pragma unroll
    for (int m = 0; m < 4; ++m) {
#pragma unroll
        for (int q = 0; q < 4; ++q) {
            int i = row0 + wm * 64 + m * 16 + ((lane >> 4) * 4) + q;
            if (i < cnt) {
                float w = s_w[e * CAP_ + i];
                short* orow = Oslot + (size_t)(e * CAP_ + i) * H_;
#pragma unroll
                for (int n = 0; n < 4; ++n)
                    orow[nc0 + wn * 64 + n * 16 + (lane & 15)] = f2bf(acc[m][n][q] * w);
            }
        }
    }
}

// ---------------- gather: out[t] = sum_k Oslot[pos[t,k]] (bf16 in, fp32 out) ----------------
__global__ __launch_bounds__(256) void k_gather(
    const short* __restrict__ Oslot, const int* __restrict__ pos,
    float* __restrict__ out)
{
    int t = blockIdx.x;
    int c = threadIdx.x * 4;
    int p0 = pos[t * 4 + 0], p1 = pos[t * 4 + 1];
    int p2 = pos[t * 4 + 2], p3 = pos[t * 4 + 3];
    f32x4 s = (f32x4){0.f, 0.f, 0.f, 0.f};
    if (p0 >= 0) {
        short4v v = *(const short4v*)&Oslot[(size_t)p0 * H_ + c];
        s[0] += bf2f(v[0]); s[1] += bf2f(v[1]); s[2] += bf2f(v[2]); s[3] += bf2f(v[3]);
    }
    if (p1 >= 0) {
        short4v v = *(const short4v*)&Oslot[(size_t)p1 * H_ + c];
        s[0] += bf2f(v[0]); s[1] += bf2f(v[1]); s[2] += bf2f(v[2]); s[3] += bf2f(v[3]);
    }
    if (p2 >= 0) {
        short4v v = *(const short4v*)&Oslot[(size_t)p2 * H_ + c];
        s[0] += bf2f(v[0]); s[1] += bf2f(v[1]); s[2] += bf2f(v[2]); s[3] += bf2f(v[3]);
    }
    if (p3 >= 0) {
        short4v v = *(const short4v*)&Oslot[(size_t)p3 * H_ + c];
        s[0] += bf2f(v[0]); s[1] += bf2f(v[1]); s[2] += bf2f(v[2]); s[3] += bf2f(v[3]);
    }
    *(f32x4*)&out[(size_t)t * H_ + c] = s;
}

// ---------------- launch ----------------

extern "C" void kernel_launch(void* const* d_in, const int* in_sizes, int n_in,
                              void* d_out, int out_size, void* d_ws, size_t ws_size,
                              hipStream_t stream) {
    const float* hs  = (const float*)d_in[0];
    const int*   tki = (const int*)d_in[1];
    const float* tkw = (const float*)d_in[2];
    const float* w1  = (const float*)d_in[3];
    const float* w2  = (const float*)d_in[4];
    float* out = (float*)d_out;

    char* ws = (char*)d_ws;
    int*   cursor = (int*)ws;                                  // 4 KB region
    int*   s_tok  = (int*)(ws + 4096);                         // 128 KB
    float* s_w    = (float*)(ws + 4096 + NSLOT_ * 4);          // 128 KB
    int*   pos    = (int*)(ws + 4096 + NSLOT_ * 8);            // 64 KB
    char*  big0   = ws + 4096 + NSLOT_ * 8 + (size_t)T_ * K_ * 4;
    short* Xb     = (short*)big0;                              // 8 MB
    short* Hb     = (short*)(big0 + (size_t)T_ * H_ * 2);      // 48 MB
    short* Oslot  = (short*)(big0 + (size_t)T_ * H_ * 2 + (size_t)NSLOT_ * I_ * 2); // 67 MB

    hipLaunchKernelGGL(k_initcast, dim3((T_ * H_) / 2048), dim3(256), 0, stream,
                       hs, Xb, cursor, s_tok, s_w);
    hipLaunchKernelGGL(k_scatter, dim3((T_ * K_) / 256), dim3(256), 0, stream,
                       tki, tkw, cursor, s_tok, s_w, pos);
    hipLaunchKernelGGL(k_gemm1, dim3(E_ * 8 * 6), dim3(512), 0, stream, Xb, w1, s_tok, cursor, Hb);
    hipLaunchKernelGGL(k_gemm2, dim3(E_ * 4 * 8), dim3(512), 0, stream, Hb, w2, s_w, cursor, Oslot);
    hipLaunchKernelGGL(k_gather, dim3(T_), dim3(256), 0, stream, Oslot, pos, out);
}

// Round 19
// 212.510 us; speedup vs baseline: 1.1074x; 1.0082x over previous
//
#include <hip/hip_runtime.h>
#include <hip/hip_bf16.h>

#define E_ 32
#define H_ 1024
#define I_ 768
#define I2_ 1536
#define T_ 4096
#define K_ 4
#define CAP_ 1024
#define NSLOT_ (E_*CAP_)

typedef __attribute__((ext_vector_type(8))) short short8;
typedef __attribute__((ext_vector_type(4))) short short4v;
typedef __attribute__((ext_vector_type(4))) float f32x4;

__device__ __forceinline__ short f2bf(float f) {
    __hip_bfloat16 h = __float2bfloat16(f);
    return __builtin_bit_cast(short, h);
}

__device__ __forceinline__ float bf2f(short s) {
    unsigned u = ((unsigned)(unsigned short)s) << 16;
    return __builtin_bit_cast(float, u);
}

typedef __attribute__((address_space(3))) void lds_void;
typedef const __attribute__((address_space(1))) void glob_void;

__device__ __forceinline__ void gload16(const void* g, void* l) {
    __builtin_amdgcn_global_load_lds((glob_void*)g, (lds_void*)l, 16, 0, 0);
}

__device__ __forceinline__ short8 cvt8(f32x4 x, f32x4 y) {
    short8 t;
    t[0]=f2bf(x[0]); t[1]=f2bf(x[1]); t[2]=f2bf(x[2]); t[3]=f2bf(x[3]);
    t[4]=f2bf(y[0]); t[5]=f2bf(y[1]); t[6]=f2bf(y[2]); t[7]=f2bf(y[3]);
    return t;
}

// ---------------- fused init + hidden-state cast ----------------
__global__ void k_initcast(const float* __restrict__ hs, short* __restrict__ Xb,
                           int* __restrict__ cursor, int* __restrict__ s_tok,
                           float* __restrict__ s_w) {
    int g = blockIdx.x * 256 + threadIdx.x;
    if (g < E_) cursor[g] = 0;
    if (g < NSLOT_) { s_tok[g] = 0; s_w[g] = 0.f; }
    const float* p = hs + (size_t)g * 8;
    f32x4 a = *(const f32x4*)p;
    f32x4 b = *(const f32x4*)(p + 4);
    *(short8*)(Xb + (size_t)g * 8) = cvt8(a, b);
}

__global__ void k_scatter(const int* __restrict__ tki, const float* __restrict__ tkw,
                          int* __restrict__ cursor, int* __restrict__ s_tok,
                          float* __restrict__ s_w, int* __restrict__ pos) {
    int n = blockIdx.x * 256 + threadIdx.x;
    if (n >= T_ * K_) return;
    int e = tki[n];
    int p = atomicAdd(cursor + e, 1);
    if (p < CAP_) {
        s_tok[e * CAP_ + p] = n >> 2;   // K_ == 4
        s_w[e * CAP_ + p]   = tkw[n];
        pos[n] = e * CAP_ + p;
    } else {
        pos[n] = -1;                    // dropped (matches reference overflow semantics)
    }
}

// ---------------- GEMM1 + SwiGLU (r15/r16-proven BN-doubled structure) ----------------
// Block 128 rows x (128 gate + 128 up), BK=64, 512 threads = 8 waves (2M x 4N).
__global__ __launch_bounds__(512) void k_gemm1(
    const short* __restrict__ Xb, const float* __restrict__ W1,
    const int* __restrict__ s_tok, const int* __restrict__ counts,
    short* __restrict__ Hb)
{
    __shared__ alignas(16) short As[128 * 64];   // 16 KB, ^(row&7) chunk swizzle
    __shared__ alignas(16) short Bs[256 * 64];   // 32 KB: rows 0-127 gate, 128-255 up

    int bid = blockIdx.x;
    bid = (bid & 7) * (1536 / 8) + (bid >> 3);   // T1 bijective XCD swizzle

    int e   = bid / 48;                          // 8 mt * 6 nt
    int rem = bid % 48;
    int mt = rem / 6, nt = rem % 6;
    int cnt = min(counts[e], CAP_);
    int row0 = mt * 128;
    if (row0 >= cnt) return;
    int gc0 = nt * 128;

    int tid = threadIdx.x, wid = tid >> 6, lane = tid & 63;
    int wm = wid >> 2, wn = wid & 3;

    unsigned offA[2];
#pragma unroll
    for (int j = 0; j < 2; ++j) {
        int cl = j * 512 + tid;
        int row = cl >> 3, cpos = cl & 7;
        int tok = s_tok[e * CAP_ + row0 + row];
        offA[j] = (unsigned)tok * H_ + ((cpos ^ (row & 7)) * 8);
    }
    const float* w1e = W1 + (size_t)e * I2_ * H_;
    unsigned gB[4]; unsigned ldsB[4];
#pragma unroll
    for (int j = 0; j < 4; ++j) {
        int cl = j * 512 + tid;
        int row = cl >> 3, cpos = cl & 7;       // row 0..255
        int wr = (row < 128) ? (gc0 + row) : (768 + gc0 + (row - 128));
        gB[j]   = (unsigned)wr * H_ + cpos * 8;
        ldsB[j] = (unsigned)row * 64 + ((cpos ^ (row & 7)) * 8);
    }

    f32x4 accg[4][2], accu[4][2];
#pragma unroll
    for (int m = 0; m < 4; ++m)
#pragma unroll
        for (int n = 0; n < 2; ++n) {
            accg[m][n] = (f32x4){0.f, 0.f, 0.f, 0.f};
            accu[m][n] = (f32x4){0.f, 0.f, 0.f, 0.f};
        }

    for (int kt = 0; kt < H_ / 64; ++kt) {
        int k0 = kt * 64;
        f32x4 b0[4], b1[4];
#pragma unroll
        for (int j = 0; j < 4; ++j) {
            const float* p = w1e + gB[j] + k0;
            b0[j] = *(const f32x4*)p;
            b1[j] = *(const f32x4*)(p + 4);
        }
#pragma unroll
        for (int j = 0; j < 2; ++j)
            gload16(Xb + offA[j] + k0, (char*)As + j * 8192 + wid * 1024);
#pragma unroll
        for (int j = 0; j < 4; ++j)
            *(short8*)&Bs[ldsB[j]] = cvt8(b0[j], b1[j]);
        __syncthreads();

#pragma unroll
        for (int kk = 0; kk < 2; ++kk) {
            short8 a[4];
#pragma unroll
            for (int m = 0; m < 4; ++m) {
                int r = wm * 64 + m * 16 + (lane & 15);
                int c = (kk * 4 + (lane >> 4)) ^ (r & 7);
                a[m] = *(const short8*)&As[r * 64 + c * 8];
            }
            short8 bg[2], bu[2];
#pragma unroll
            for (int n = 0; n < 2; ++n) {
                int brg = wn * 32 + n * 16 + (lane & 15);
                int cg = (kk * 4 + (lane >> 4)) ^ (brg & 7);
                bg[n] = *(const short8*)&Bs[brg * 64 + cg * 8];
                int bru = 128 + wn * 32 + n * 16 + (lane & 15);
                int cu = (kk * 4 + (lane >> 4)) ^ (bru & 7);
                bu[n] = *(const short8*)&Bs[bru * 64 + cu * 8];
            }
#pragma unroll
            for (int m = 0; m < 4; ++m)
#pragma unroll
                for (int n = 0; n < 2; ++n) {
                    accg[m][n] = __builtin_amdgcn_mfma_f32_16x16x32_bf16(a[m], bg[n], accg[m][n], 0, 0, 0);
                    accu[m][n] = __builtin_amdgcn_mfma_f32_16x16x32_bf16(a[m], bu[n], accu[m][n], 0, 0, 0);
                }
        }
        __syncthreads();
    }

    // SwiGLU epilogue
#pragma unroll
    for (int m = 0; m < 4; ++m) {
        int rb = row0 + wm * 64 + m * 16 + ((lane >> 4) * 4);
#pragma unroll
        for (int n = 0; n < 2; ++n) {
            int col = gc0 + wn * 32 + n * 16 + (lane & 15);
#pragma unroll
            for (int q = 0; q < 4; ++q) {
                float g = accg[m][n][q], u = accu[m][n][q];
                float h = (g / (1.f + __expf(-g))) * u;
                Hb[(size_t)(e * CAP_ + rb + q) * I_ + col] = f2bf(h);
            }
        }
    }
}

// ---------------- GEMM2 -> Oslot bf16 (r16-proven) ----------------
// Block 256 rows x 128 H-cols, BK=64, 512 threads = 8 waves (4M x 2N); wave 64x64. 48 KB LDS.
__global__ __launch_bounds__(512) void k_gemm2(
    const short* __restrict__ Hb, const float* __restrict__ W2,
    const float* __restrict__ s_w, const int* __restrict__ counts,
    short* __restrict__ Oslot)
{
    __shared__ alignas(16) short Ah[256 * 64];   // 32 KB
    __shared__ alignas(16) short Bs[128 * 64];   // 16 KB

    int bid = blockIdx.x;
    bid = (bid & 7) * (1024 / 8) + (bid >> 3);   // T1 bijective XCD swizzle

    int e = bid / 32;                            // 4 mt * 8 nt
    int rem = bid % 32;
    int mt = rem / 8, nt = rem % 8;
    int cnt = min(counts[e], CAP_);
    int row0 = mt * 256;
    if (row0 >= cnt) return;
    int nc0 = nt * 128;

    int tid = threadIdx.x, wid = tid >> 6, lane = tid & 63;
    int wm = wid >> 1, wn = wid & 1;

    unsigned offA[4];
#pragma unroll
    for (int j = 0; j < 4; ++j) {
        int cl = j * 512 + tid;
        int row = cl >> 3, cpos = cl & 7;
        offA[j] = (unsigned)(e * CAP_ + row0 + row) * I_ + ((cpos ^ (row & 7)) * 8);
    }
    const float* w2e = W2 + (size_t)e * H_ * I_;
    unsigned gB[2]; unsigned ldsB[2];
#pragma unroll
    for (int j = 0; j < 2; ++j) {
        int cl = j * 512 + tid;
        int row = cl >> 3, cpos = cl & 7;
        gB[j]   = (unsigned)(nc0 + row) * I_ + cpos * 8;
        ldsB[j] = (unsigned)row * 64 + ((cpos ^ (row & 7)) * 8);
    }

    f32x4 acc[4][4];
#pragma unroll
    for (int m = 0; m < 4; ++m)
#pragma unroll
        for (int n = 0; n < 4; ++n) acc[m][n] = (f32x4){0.f, 0.f, 0.f, 0.f};

    for (int kt = 0; kt < I_ / 64; ++kt) {
        int k0 = kt * 64;
        f32x4 b0[2], b1[2];
#pragma unroll
        for (int j = 0; j < 2; ++j) {
            const float* p = w2e + gB[j] + k0;
            b0[j] = *(const f32x4*)p;
            b1[j] = *(const f32x4*)(p + 4);
        }
#pragma unroll
        for (int j = 0; j < 4; ++j)
            gload16(Hb + offA[j] + k0, (char*)Ah + j * 8192 + wid * 1024);
#pragma unroll
        for (int j = 0; j < 2; ++j)
            *(short8*)&Bs[ldsB[j]] = cvt8(b0[j], b1[j]);
        __syncthreads();

#pragma unroll
        for (int kk = 0; kk < 2; ++kk) {
            short8 a[4];
#pragma unroll
            for (int m = 0; m < 4; ++m) {
                int r = wm * 64 + m * 16 + (lane & 15);
                int c = (kk * 4 + (lane >> 4)) ^ (r & 7);
                a[m] = *(const short8*)&Ah[r * 64 + c * 8];
            }
            short8 b[4];
#pragma unroll
            for (int n = 0; n < 4; ++n) {
                int br = wn * 64 + n * 16 + (lane & 15);
                int c = (kk * 4 + (lane >> 4)) ^ (br & 7);
                b[n] = *(const short8*)&Bs[br * 64 + c * 8];
            }
#pragma unroll
            for (int m = 0; m < 4; ++m)
#pragma unroll
                for (int n = 0; n < 4; ++n)
                    acc[m][n] = __builtin_amdgcn_mfma_f32_16x16x32_bf16(a[m], b[n], acc[m][n], 0, 0, 0);
        }
        __syncthreads();
    }

#pragma unroll
    for (int m = 0; m < 4; ++m) {
#pragma unroll
        for (int q = 0; q < 4; ++q) {
            int i = row0 + wm * 64 + m * 16 + ((lane >> 4) * 4) + q;
            if (i < cnt) {
                float w = s_w[e * CAP_ + i];
                short* orow = Oslot + (size_t)(e * CAP_ + i) * H_;
#pragma unroll
                for (int n = 0; n < 4; ++n)
                    orow[nc0 + wn * 64 + n * 16 + (lane & 15)] = f2bf(acc[m][n][q] * w);
            }
        }
    }
}

// ---------------- gather: out[t] = sum_k Oslot[pos[t,k]] (16B loads, 2 tokens/block) ----------------
__global__ __launch_bounds__(256) void k_gather(
    const short* __restrict__ Oslot, const int* __restrict__ pos,
    float* __restrict__ out)
{
    int t = blockIdx.x * 2 + (threadIdx.x >> 7);
    int c = (threadIdx.x & 127) * 8;
    int p0 = pos[t * 4 + 0], p1 = pos[t * 4 + 1];
    int p2 = pos[t * 4 + 2], p3 = pos[t * 4 + 3];
    f32x4 s0 = (f32x4){0.f, 0.f, 0.f, 0.f};
    f32x4 s1 = (f32x4){0.f, 0.f, 0.f, 0.f};
    if (p0 >= 0) {
        short8 v = *(const short8*)&Oslot[(size_t)p0 * H_ + c];
        s0[0]+=bf2f(v[0]); s0[1]+=bf2f(v[1]); s0[2]+=bf2f(v[2]); s0[3]+=bf2f(v[3]);
        s1[0]+=bf2f(v[4]); s1[1]+=bf2f(v[5]); s1[2]+=bf2f(v[6]); s1[3]+=bf2f(v[7]);
    }
    if (p1 >= 0) {
        short8 v = *(const short8*)&Oslot[(size_t)p1 * H_ + c];
        s0[0]+=bf2f(v[0]); s0[1]+=bf2f(v[1]); s0[2]+=bf2f(v[2]); s0[3]+=bf2f(v[3]);
        s1[0]+=bf2f(v[4]); s1[1]+=bf2f(v[5]); s1[2]+=bf2f(v[6]); s1[3]+=bf2f(v[7]);
    }
    if (p2 >= 0) {
        short8 v = *(const short8*)&Oslot[(size_t)p2 * H_ + c];
        s0[0]+=bf2f(v[0]); s0[1]+=bf2f(v[1]); s0[2]+=bf2f(v[2]); s0[3]+=bf2f(v[3]);
        s1[0]+=bf2f(v[4]); s1[1]+=bf2f(v[5]); s1[2]+=bf2f(v[6]); s1[3]+=bf2f(v[7]);
    }
    if (p3 >= 0) {
        short8 v = *(const short8*)&Oslot[(size_t)p3 * H_ + c];
        s0[0]+=bf2f(v[0]); s0[1]+=bf2f(v[1]); s0[2]+=bf2f(v[2]); s0[3]+=bf2f(v[3]);
        s1[0]+=bf2f(v[4]); s1[1]+=bf2f(v[5]); s1[2]+=bf2f(v[6]); s1[3]+=bf2f(v[7]);
    }
    *(f32x4*)&out[(size_t)t * H_ + c] = s0;
    *(f32x4*)&out[(size_t)t * H_ + c + 4] = s1;
}

// ---------------- launch ----------------

extern "C" void kernel_launch(void* const* d_in, const int* in_sizes, int n_in,
                              void* d_out, int out_size, void* d_ws, size_t ws_size,
                              hipStream_t stream) {
    const float* hs  = (const float*)d_in[0];
    const int*   tki = (const int*)d_in[1];
    const float* tkw = (const float*)d_in[2];
    const float* w1  = (const float*)d_in[3];
    const float* w2  = (const float*)d_in[4];
    float* out = (float*)d_out;

    char* ws = (char*)d_ws;
    int*   cursor = (int*)ws;                                  // 4 KB region
    int*   s_tok  = (int*)(ws + 4096);                         // 128 KB
    float* s_w    = (float*)(ws + 4096 + NSLOT_ * 4);          // 128 KB
    int*   pos    = (int*)(ws + 4096 + NSLOT_ * 8);            // 64 KB
    char*  big0   = ws + 4096 + NSLOT_ * 8 + (size_t)T_ * K_ * 4;
    short* Xb     = (short*)big0;                              // 8 MB
    short* Hb     = (short*)(big0 + (size_t)T_ * H_ * 2);      // 48 MB
    short* Oslot  = (short*)(big0 + (size_t)T_ * H_ * 2 + (size_t)NSLOT_ * I_ * 2); // 67 MB

    hipLaunchKernelGGL(k_initcast, dim3((T_ * H_) / 2048), dim3(256), 0, stream,
                       hs, Xb, cursor, s_tok, s_w);
    hipLaunchKernelGGL(k_scatter, dim3((T_ * K_) / 256), dim3(256), 0, stream,
                       tki, tkw, cursor, s_tok, s_w, pos);
    hipLaunchKernelGGL(k_gemm1, dim3(E_ * 8 * 6), dim3(512), 0, stream, Xb, w1, s_tok, cursor, Hb);
    hipLaunchKernelGGL(k_gemm2, dim3(E_ * 4 * 8), dim3(512), 0, stream, Hb, w2, s_w, cursor, Oslot);
    hipLaunchKernelGGL(k_gather, dim3(T_ / 2), dim3(256), 0, stream, Oslot, pos, out);
}